// Round 7
// baseline (249.452 us; speedup 1.0000x reference)
//
#include <hip/hip_runtime.h>

#define NN 50000
#define EE 1600000
#define FF 48
#define RR 8
#define H2R 48                          // bf16 per (n,r) row, packed (96 B), rel-major
#define LSTR 72                         // LDS H1 row stride (bf16)
#define NSEG 8                          // sub-buckets per node (one per XCD)
#define SCAP 16                         // slots per sub-bucket (= one 64-B line)
#define OVF_CAP 65536                   // overflow list entries (uint2)

#define WB 8                            // weight transpose blocks (1 per rel)
#define ZB 391                          // zero blocks: ceil(100001 int4/256)
#define K1GRID (WB + ZB)

#define H2TILES 391                     // ceil(50000/128) node tiles, ALL 8 rels each
#define PB ((EE + 255) / 256)           // 6250 place blocks, 1 edge/thread

typedef __attribute__((ext_vector_type(8))) short frag8;
typedef __attribute__((ext_vector_type(4))) float frag4f;
typedef __attribute__((ext_vector_type(4))) unsigned uint4v;
typedef __attribute__((ext_vector_type(4))) float float4v;

__device__ inline unsigned short bf16r(float f) {
    unsigned u = __float_as_uint(f);
    return (unsigned short)((u + 0x7FFFu + ((u >> 16) & 1u)) >> 16);  // RNE
}
__device__ inline unsigned bf16pack2(float a, float b) {
    return (unsigned)bf16r(a) | ((unsigned)bf16r(b) << 16);
}
__device__ inline frag8 pack8(float4v a, float4v b) {
    union { frag8 f; unsigned u[4]; } r;
    r.u[0] = bf16pack2(a.x, a.y); r.u[1] = bf16pack2(a.z, a.w);
    r.u[2] = bf16pack2(b.x, b.y); r.u[3] = bf16pack2(b.z, b.w);
    return r.f;
}

// ---- k1: W1/W2 -> bf16 transposed (blocks 0..7) + zero count/ovf_cnt -------
__global__ __launch_bounds__(256) void pre_kernel(
    const float* __restrict__ W1, const float* __restrict__ W2,
    unsigned short* __restrict__ W1t, unsigned short* __restrict__ W2t,
    int* __restrict__ count)
{
    int b = blockIdx.x;
    if (b < WB) {
        int r = b;
        const float* w1 = W1 + (size_t)r * FF * FF;
        const float* w2 = W2 + (size_t)r * FF * FF;
        for (int idx = threadIdx.x; idx < 48 * 64; idx += 256) {
            int j = idx >> 6, k = idx & 63;
            W1t[(size_t)r * 48 * 64 + idx] = (k < FF) ? bf16r(w1[k * FF + j]) : (unsigned short)0;
            W2t[(size_t)r * 48 * 64 + idx] = (k < FF) ? bf16r(w2[k * FF + j]) : (unsigned short)0;
        }
        return;
    }
    // zero count[NSEG*NN] + ovf_cnt (+pad): 400004 ints = 100001 int4
    int z = (b - WB) * 256 + threadIdx.x;
    if (z < 100001) ((int4*)count)[z] = make_int4(0, 0, 0, 0);
}

// ---- k2: place ONLY (round-7 split). Rationale: in the fused kernel, the
// H2 stream evicted payload bucket lines between record arrivals -> each
// 64-B line written back ~4x partially = ~100 MB scattered 64-B HBM writes
// at ~1.5 TB/s = the invariant ~87 us. Alone, the per-XCD working set
// (3.2 MB payload slice + 0.2 MB count) is L2-resident with only nt edge
// reads competing: lines accumulate all records and write back ONCE.
__global__ __launch_bounds__(256) void place_kernel(
    const int* __restrict__ srcv, const int* __restrict__ dstv,
    const int* __restrict__ relv, const float* __restrict__ norm,
    int* __restrict__ count, int* __restrict__ ovf_cnt,
    uint2* __restrict__ ovf, unsigned* __restrict__ payload)
{
    int e = blockIdx.x * 256 + threadIdx.x;
    if (e >= EE) return;
    int xcd;
    asm volatile("s_getreg_b32 %0, hwreg(HW_REG_XCC_ID)" : "=s"(xcd));
    xcd &= (NSEG - 1);
    int d  = __builtin_nontemporal_load(&dstv[e]);
    int sv = __builtin_nontemporal_load(&srcv[e]);
    int rv = __builtin_nontemporal_load(&relv[e]);
    float nmv = __builtin_nontemporal_load(&norm[e]);
    unsigned qn = (unsigned)(nmv * 8192.0f + 0.5f);
    if (qn > 8191u) qn = 8191u;
    unsigned rec = ((unsigned)(rv * NN + sv) << 13) | qn;
    int pos = __hip_atomic_fetch_add(&count[xcd * NN + d], 1,
                                     __ATOMIC_RELAXED,
                                     __HIP_MEMORY_SCOPE_WORKGROUP);
    if (pos < SCAP) {
        payload[((size_t)xcd * NN + d) * SCAP + pos] = rec;
    } else {                                     // rare: agent-scope list
        int oi = atomicAdd(ovf_cnt, 1);
        if (oi < OVF_CAP) ovf[oi] = make_uint2((unsigned)d, rec);
    }
}

// ---- k3: h2 ONLY (391 blocks: 128 nodes x ALL 8 rels; round-4 proven form:
// X once, 18-KB LDS, in-place stage-2 image, contiguous rel-major stores) ----
__global__ __launch_bounds__(256) void h2_kernel(
    const float* __restrict__ X, const unsigned short* __restrict__ W1t,
    const unsigned short* __restrict__ W2t, const float* __restrict__ B1,
    unsigned short* __restrict__ H2)
{
    __shared__ __align__(16) unsigned short h1s[128 * LSTR];   // 18 KB
    int b = blockIdx.x;
    int tid  = threadIdx.x;
    int w    = tid >> 6, ln = tid & 63, q = ln >> 4, lq = ln & 15;
    int nb   = b * 128 + w * 32;                     // this wave's 32 nodes

    unsigned short* myh1 = &h1s[(w * 32) * LSTR];
    for (int i = ln; i < 32 * 12; i += 64) {         // zero h1 K-pad once (NaN guard)
        int rr = i / 12, cs = i - rr * 12;
        *(unsigned*)&myh1[rr * LSTR + 48 + cs * 2] = 0;
    }

    int row0 = nb + lq;      if (row0 >= NN) row0 = NN - 1;
    int row1 = nb + 16 + lq; if (row1 >= NN) row1 = NN - 1;
    const float4v* x0 = (const float4v*)(X + (size_t)row0 * FF);
    const float4v* x1 = (const float4v*)(X + (size_t)row1 * FF);

    frag8 a00 = pack8(__builtin_nontemporal_load(x0 + q * 2),
                      __builtin_nontemporal_load(x0 + q * 2 + 1));
    frag8 a10 = pack8(__builtin_nontemporal_load(x1 + q * 2),
                      __builtin_nontemporal_load(x1 + q * 2 + 1));
    frag8 a01 = {0, 0, 0, 0, 0, 0, 0, 0};
    frag8 a11 = {0, 0, 0, 0, 0, 0, 0, 0};
    if (q < 2) {
        a01 = pack8(__builtin_nontemporal_load(x0 + 8 + q * 2),
                    __builtin_nontemporal_load(x0 + 9 + q * 2));
        a11 = pack8(__builtin_nontemporal_load(x1 + 8 + q * 2),
                    __builtin_nontemporal_load(x1 + 9 + q * 2));
    }

    float bcv[3] = {B1[lq], B1[16 + lq], B1[32 + lq]};

    #pragma unroll 1
    for (int r = 0; r < RR; ++r) {
        const unsigned short* w1r = W1t + (size_t)r * 48 * 64;
        const unsigned short* w2r = W2t + (size_t)r * 48 * 64;

        #pragma unroll
        for (int t = 0; t < 3; ++t) {                // stage 1 -> LDS h1
            int col = t * 16 + lq;
            frag8 b0 = *(const frag8*)&w1r[(col << 6) + q * 8];
            frag8 b1 = *(const frag8*)&w1r[(col << 6) + 32 + q * 8];
            float bc = bcv[t];
            frag4f acc0 = {bc, bc, bc, bc};
            frag4f acc1 = {bc, bc, bc, bc};
            acc0 = __builtin_amdgcn_mfma_f32_16x16x32_bf16(a00, b0, acc0, 0, 0, 0);
            acc0 = __builtin_amdgcn_mfma_f32_16x16x32_bf16(a01, b1, acc0, 0, 0, 0);
            acc1 = __builtin_amdgcn_mfma_f32_16x16x32_bf16(a10, b0, acc1, 0, 0, 0);
            acc1 = __builtin_amdgcn_mfma_f32_16x16x32_bf16(a11, b1, acc1, 0, 0, 0);
            #pragma unroll
            for (int g = 0; g < 4; ++g) {            // C/D: row=q*4+g, col=lane&15
                myh1[(q * 4 + g) * LSTR + col]      = bf16r(fmaxf(acc0[g], 0.0f));
                myh1[(16 + q * 4 + g) * LSTR + col] = bf16r(fmaxf(acc1[g], 0.0f));
            }
        }

        const frag8 c00 = *(const frag8*)&myh1[lq * LSTR + q * 8];
        const frag8 c01 = *(const frag8*)&myh1[lq * LSTR + 32 + q * 8];
        const frag8 c10 = *(const frag8*)&myh1[(16 + lq) * LSTR + q * 8];
        const frag8 c11 = *(const frag8*)&myh1[(16 + lq) * LSTR + 32 + q * 8];

        #pragma unroll
        for (int t = 0; t < 3; ++t) {                // stage 2 -> image in slab
            int col = t * 16 + lq;                   // (same LSTR stride: pads live)
            frag8 b0 = *(const frag8*)&w2r[(col << 6) + q * 8];
            frag8 b1 = *(const frag8*)&w2r[(col << 6) + 32 + q * 8];
            frag4f acc0 = {0.f, 0.f, 0.f, 0.f};
            frag4f acc1 = {0.f, 0.f, 0.f, 0.f};
            acc0 = __builtin_amdgcn_mfma_f32_16x16x32_bf16(c00, b0, acc0, 0, 0, 0);
            acc0 = __builtin_amdgcn_mfma_f32_16x16x32_bf16(c01, b1, acc0, 0, 0, 0);
            acc1 = __builtin_amdgcn_mfma_f32_16x16x32_bf16(c10, b0, acc1, 0, 0, 0);
            acc1 = __builtin_amdgcn_mfma_f32_16x16x32_bf16(c11, b1, acc1, 0, 0, 0);
            #pragma unroll
            for (int g = 0; g < 4; ++g) {
                myh1[(q * 4 + g) * LSTR + col]      = bf16r(acc0[g]);
                myh1[(16 + q * 4 + g) * LSTR + col] = bf16r(acc1[g]);
            }
        }

        // copy-out: 32 rows x 96 B = 3072 contiguous bytes in rel-major H2;
        // plain stores -> L2 write-combines fully-dirty lines, one writeback.
        unsigned short* dst = H2 + ((size_t)r * NN + nb) * H2R;
        #pragma unroll
        for (int i3 = 0; i3 < 3; ++i3) {
            int fl    = i3 * 64 + ln;                // 0..191 uint4v pieces
            int row   = fl / 6, piece = fl - row * 6;
            int n     = nb + row;
            if (n < NN)
                *(uint4v*)(dst + fl * 8) =
                    *(const uint4v*)&myh1[row * LSTR + piece * 8];
        }
    }
}

// ---- gather: 12 lanes/node; unroll 16 for more outstanding random loads -----
__global__ __launch_bounds__(256) void gather_kernel(
    const unsigned short* __restrict__ H2, const unsigned* __restrict__ payload,
    const int* __restrict__ count, const int* __restrict__ ovf_cnt,
    const uint2* __restrict__ ovf, const float* __restrict__ B2,
    float* __restrict__ out)
{
    unsigned tid = blockIdx.x * 256u + threadIdx.x;
    unsigned n = tid / 12u;
    unsigned c = tid - n * 12u;
    if (n >= NN) return;

    int cx[NSEG];
    #pragma unroll
    for (int x = 0; x < NSEG; ++x) cx[x] = min(count[(size_t)x * NN + n], SCAP);
    int p1 = cx[0], p2 = p1 + cx[1], p3 = p2 + cx[2], p4 = p3 + cx[3];
    int p5 = p4 + cx[4], p6 = p5 + cx[5], p7 = p6 + cx[6];
    int total = p7 + cx[7];
    const unsigned* pl = payload + (size_t)n * SCAP;   // x slice adds x*NN*SCAP

    auto slot = [&](int idx) -> unsigned {
        int x, base;
        if (idx < p4) {
            if (idx < p2) { x = (idx < p1) ? 0 : 1; base = (idx < p1) ? 0 : p1; }
            else          { x = (idx < p3) ? 2 : 3; base = (idx < p3) ? p2 : p3; }
        } else {
            if (idx < p6) { x = (idx < p5) ? 4 : 5; base = (idx < p5) ? p4 : p5; }
            else          { x = (idx < p7) ? 6 : 7; base = (idx < p7) ? p6 : p7; }
        }
        return pl[(size_t)x * (NN * SCAP) + (idx - base)];
    };

    float a0 = 0.f, a1 = 0.f, a2 = 0.f, a3 = 0.f;
    int e = 0;
    for (; e + 16 <= total; e += 16) {
        unsigned p[16];
        #pragma unroll
        for (int k = 0; k < 16; ++k) p[k] = slot(e + k);
        uint2 v[16];
        #pragma unroll
        for (int k = 0; k < 16; ++k)
            v[k] = ((const uint2*)(H2 + (size_t)(p[k] >> 13) * H2R))[c];
        #pragma unroll
        for (int k = 0; k < 16; ++k) {
            float nm = (float)(p[k] & 8191u) * (1.0f / 8192.0f);
            a0 = fmaf(__uint_as_float(v[k].x << 16),         nm, a0);
            a1 = fmaf(__uint_as_float(v[k].x & 0xFFFF0000u), nm, a1);
            a2 = fmaf(__uint_as_float(v[k].y << 16),         nm, a2);
            a3 = fmaf(__uint_as_float(v[k].y & 0xFFFF0000u), nm, a3);
        }
    }
    for (; e + 8 <= total; e += 8) {
        unsigned p[8];
        #pragma unroll
        for (int k = 0; k < 8; ++k) p[k] = slot(e + k);
        uint2 v[8];
        #pragma unroll
        for (int k = 0; k < 8; ++k)
            v[k] = ((const uint2*)(H2 + (size_t)(p[k] >> 13) * H2R))[c];
        #pragma unroll
        for (int k = 0; k < 8; ++k) {
            float nm = (float)(p[k] & 8191u) * (1.0f / 8192.0f);
            a0 = fmaf(__uint_as_float(v[k].x << 16),         nm, a0);
            a1 = fmaf(__uint_as_float(v[k].x & 0xFFFF0000u), nm, a1);
            a2 = fmaf(__uint_as_float(v[k].y << 16),         nm, a2);
            a3 = fmaf(__uint_as_float(v[k].y & 0xFFFF0000u), nm, a3);
        }
    }
    for (; e < total; ++e) {
        unsigned p = slot(e);
        float nm = (float)(p & 8191u) * (1.0f / 8192.0f);
        uint2 v = ((const uint2*)(H2 + (size_t)(p >> 13) * H2R))[c];
        a0 = fmaf(__uint_as_float(v.x << 16),         nm, a0);
        a1 = fmaf(__uint_as_float(v.x & 0xFFFF0000u), nm, a1);
        a2 = fmaf(__uint_as_float(v.y << 16),         nm, a2);
        a3 = fmaf(__uint_as_float(v.y & 0xFFFF0000u), nm, a3);
    }
    // overflow list (typically empty): add entries targeting this node
    int ov = *ovf_cnt;
    if (ov > 0) {
        if (ov > OVF_CAP) ov = OVF_CAP;
        for (int i = 0; i < ov; ++i) {
            uint2 t = ovf[i];
            if (t.x == n) {
                float nm = (float)(t.y & 8191u) * (1.0f / 8192.0f);
                uint2 v = ((const uint2*)(H2 + (size_t)(t.y >> 13) * H2R))[c];
                a0 = fmaf(__uint_as_float(v.x << 16),         nm, a0);
                a1 = fmaf(__uint_as_float(v.x & 0xFFFF0000u), nm, a1);
                a2 = fmaf(__uint_as_float(v.y << 16),         nm, a2);
                a3 = fmaf(__uint_as_float(v.y & 0xFFFF0000u), nm, a3);
            }
        }
    }
    float4 bbb = ((const float4*)B2)[c];
    ((float4*)out)[(size_t)n * 12u + c] = make_float4(
        fmaxf(a0 + bbb.x, 0.f), fmaxf(a1 + bbb.y, 0.f),
        fmaxf(a2 + bbb.z, 0.f), fmaxf(a3 + bbb.w, 0.f));
}

extern "C" void kernel_launch(void* const* d_in, const int* in_sizes, int n_in,
                              void* d_out, int out_size, void* d_ws, size_t ws_size,
                              hipStream_t stream) {
    const float* X   = (const float*)d_in[0];
    const float* nrm = (const float*)d_in[1];
    const float* W1  = (const float*)d_in[2];
    const float* W2  = (const float*)d_in[3];
    const float* B1  = (const float*)d_in[4];
    const float* B2  = (const float*)d_in[5];
    const int*   src = (const int*)d_in[6];
    const int*   dst = (const int*)d_in[7];
    const int*   rel = (const int*)d_in[8];
    float* out = (float*)d_out;

    // ws: H2 38.4MB | payload 25.6MB | W1t/W2t 96KB | count 1.6MB | ovf 512KB
    unsigned short* H2      = (unsigned short*)d_ws;
    unsigned*       payload = (unsigned*)(H2 + (size_t)NN * RR * H2R);
    unsigned short* W1t     = (unsigned short*)(payload + (size_t)NN * NSEG * SCAP);
    unsigned short* W2t     = W1t + RR * 48 * 64;
    int*            count   = (int*)(W2t + RR * 48 * 64);
    int*            ovf_cnt = count + (size_t)NSEG * NN;          // zeroed with count
    uint2*          ovf     = (uint2*)(count + (size_t)NSEG * NN + 4);

    pre_kernel<<<K1GRID, 256, 0, stream>>>(W1, W2, W1t, W2t, count);

    place_kernel<<<PB, 256, 0, stream>>>(
        src, dst, rel, nrm, count, ovf_cnt, ovf, payload);

    h2_kernel<<<H2TILES, 256, 0, stream>>>(X, W1t, W2t, B1, H2);

    unsigned total = (unsigned)NN * 12u;
    gather_kernel<<<(total + 255) / 256, 256, 0, stream>>>(
        H2, payload, count, ovf_cnt, ovf, B2, out);
}

// Round 8
// 236.848 us; speedup vs baseline: 1.0532x; 1.0532x over previous
//
#include <hip/hip_runtime.h>

#define NN 50000
#define EE 1600000
#define FF 48
#define RR 8
#define H2R 48                          // bf16 per (n,r) row, packed (96 B), rel-major
#define LSTR 72                         // LDS H1 row stride (bf16)
#define NSEG 8                          // FIFO segments (one per XCD)
#define NB 3125                         // dst buckets of 16 nodes (50000/16)
#define FCAP 128                        // entries per (xcd,bucket) segment (mean 64, +8 sigma)
#define LCAP 72                         // per-node LDS list cap (max degree ~58)
#define OVF_CAP 65536                   // overflow list entries (uint2)

#define WB 8                            // weight transpose blocks (1 per rel)
#define ZB 25                           // zero blocks: ceil(6251 int4/256)
#define K1GRID (WB + ZB)

#define H2TILES 391                     // ceil(50000/128) node tiles, ALL 8 rels each
#define PB ((EE + 255) / 256)           // 6250 place blocks, 1 edge/thread

typedef __attribute__((ext_vector_type(8))) short frag8;
typedef __attribute__((ext_vector_type(4))) float frag4f;
typedef __attribute__((ext_vector_type(4))) unsigned uint4v;
typedef __attribute__((ext_vector_type(4))) float float4v;

__device__ inline unsigned short bf16r(float f) {
    unsigned u = __float_as_uint(f);
    return (unsigned short)((u + 0x7FFFu + ((u >> 16) & 1u)) >> 16);  // RNE
}
__device__ inline unsigned bf16pack2(float a, float b) {
    return (unsigned)bf16r(a) | ((unsigned)bf16r(b) << 16);
}
__device__ inline frag8 pack8(float4v a, float4v b) {
    union { frag8 f; unsigned u[4]; } r;
    r.u[0] = bf16pack2(a.x, a.y); r.u[1] = bf16pack2(a.z, a.w);
    r.u[2] = bf16pack2(b.x, b.y); r.u[3] = bf16pack2(b.z, b.w);
    return r.f;
}

// ---- k1: W1/W2 -> bf16 transposed (blocks 0..7) + zero cur/ovf_cnt ---------
__global__ __launch_bounds__(256) void pre_kernel(
    const float* __restrict__ W1, const float* __restrict__ W2,
    unsigned short* __restrict__ W1t, unsigned short* __restrict__ W2t,
    int* __restrict__ cur)
{
    int b = blockIdx.x;
    if (b < WB) {
        int r = b;
        const float* w1 = W1 + (size_t)r * FF * FF;
        const float* w2 = W2 + (size_t)r * FF * FF;
        for (int idx = threadIdx.x; idx < 48 * 64; idx += 256) {
            int j = idx >> 6, k = idx & 63;
            W1t[(size_t)r * 48 * 64 + idx] = (k < FF) ? bf16r(w1[k * FF + j]) : (unsigned short)0;
            W2t[(size_t)r * 48 * 64 + idx] = (k < FF) ? bf16r(w2[k * FF + j]) : (unsigned short)0;
        }
        return;
    }
    // zero cur[NSEG*NB] + ovf_cnt (+pad): 25004 ints = 6251 int4
    int z = (b - WB) * 256 + threadIdx.x;
    if (z < 6251) ((int4*)cur)[z] = make_int4(0, 0, 0, 0);
}

// ---- k2: place = append-FIFO scatter (round-8 restructure) -----------------
// R7 proved the per-node random-slot scatter is intrinsically ~93 MB of
// partial-line writebacks (each line's ~4 records arrive spread across the
// whole kernel; no cache can hold all 50K lines). Append FIFOs fix the
// MECHANISM: cursor grants are sequential in time, so each 64-B line fills
// with 8 consecutive records; only the OPEN tail line per bucket needs L2
// residency (3125 x 64 B = 200 KB/XCD). Filled lines evict fully-dirty ->
// exactly one writeback. Per-XCD segments keep lines single-L2-owned.
__global__ __launch_bounds__(256) void place_kernel(
    const int* __restrict__ srcv, const int* __restrict__ dstv,
    const int* __restrict__ relv, const float* __restrict__ norm,
    int* __restrict__ cur, int* __restrict__ ovf_cnt,
    uint2* __restrict__ ovf, uint2* __restrict__ fifo)
{
    int e = blockIdx.x * 256 + threadIdx.x;
    if (e >= EE) return;
    int xcd;
    asm volatile("s_getreg_b32 %0, hwreg(HW_REG_XCC_ID)" : "=s"(xcd));
    xcd &= (NSEG - 1);
    int d  = __builtin_nontemporal_load(&dstv[e]);
    int sv = __builtin_nontemporal_load(&srcv[e]);
    int rv = __builtin_nontemporal_load(&relv[e]);
    float nmv = __builtin_nontemporal_load(&norm[e]);
    unsigned qn = (unsigned)(nmv * 8192.0f + 0.5f);
    if (qn > 8191u) qn = 8191u;
    unsigned rec = ((unsigned)(rv * NN + sv) << 13) | qn;
    int bkt = d >> 4;                                // 16-node bucket
    int seg = xcd * NB + bkt;
    int pos = __hip_atomic_fetch_add(&cur[seg], 1,
                                     __ATOMIC_RELAXED,
                                     __HIP_MEMORY_SCOPE_WORKGROUP);
    if (pos < FCAP) {
        fifo[(size_t)seg * FCAP + pos] = make_uint2(rec, (unsigned)(d & 15));
    } else {                                         // ~never: agent-scope list
        int oi = atomicAdd(ovf_cnt, 1);
        if (oi < OVF_CAP) ovf[oi] = make_uint2((unsigned)d, rec);
    }
}

// ---- k3: h2 (391 blocks: 128 nodes x ALL 8 rels; R4-proven form) -----------
__global__ __launch_bounds__(256) void h2_kernel(
    const float* __restrict__ X, const unsigned short* __restrict__ W1t,
    const unsigned short* __restrict__ W2t, const float* __restrict__ B1,
    unsigned short* __restrict__ H2)
{
    __shared__ __align__(16) unsigned short h1s[128 * LSTR];   // 18 KB
    int b = blockIdx.x;
    int tid  = threadIdx.x;
    int w    = tid >> 6, ln = tid & 63, q = ln >> 4, lq = ln & 15;
    int nb   = b * 128 + w * 32;                     // this wave's 32 nodes

    unsigned short* myh1 = &h1s[(w * 32) * LSTR];
    for (int i = ln; i < 32 * 12; i += 64) {         // zero h1 K-pad once (NaN guard)
        int rr = i / 12, cs = i - rr * 12;
        *(unsigned*)&myh1[rr * LSTR + 48 + cs * 2] = 0;
    }

    int row0 = nb + lq;      if (row0 >= NN) row0 = NN - 1;
    int row1 = nb + 16 + lq; if (row1 >= NN) row1 = NN - 1;
    const float4v* x0 = (const float4v*)(X + (size_t)row0 * FF);
    const float4v* x1 = (const float4v*)(X + (size_t)row1 * FF);

    frag8 a00 = pack8(__builtin_nontemporal_load(x0 + q * 2),
                      __builtin_nontemporal_load(x0 + q * 2 + 1));
    frag8 a10 = pack8(__builtin_nontemporal_load(x1 + q * 2),
                      __builtin_nontemporal_load(x1 + q * 2 + 1));
    frag8 a01 = {0, 0, 0, 0, 0, 0, 0, 0};
    frag8 a11 = {0, 0, 0, 0, 0, 0, 0, 0};
    if (q < 2) {
        a01 = pack8(__builtin_nontemporal_load(x0 + 8 + q * 2),
                    __builtin_nontemporal_load(x0 + 9 + q * 2));
        a11 = pack8(__builtin_nontemporal_load(x1 + 8 + q * 2),
                    __builtin_nontemporal_load(x1 + 9 + q * 2));
    }

    float bcv[3] = {B1[lq], B1[16 + lq], B1[32 + lq]};

    #pragma unroll 1
    for (int r = 0; r < RR; ++r) {
        const unsigned short* w1r = W1t + (size_t)r * 48 * 64;
        const unsigned short* w2r = W2t + (size_t)r * 48 * 64;

        #pragma unroll
        for (int t = 0; t < 3; ++t) {                // stage 1 -> LDS h1
            int col = t * 16 + lq;
            frag8 b0 = *(const frag8*)&w1r[(col << 6) + q * 8];
            frag8 b1 = *(const frag8*)&w1r[(col << 6) + 32 + q * 8];
            float bc = bcv[t];
            frag4f acc0 = {bc, bc, bc, bc};
            frag4f acc1 = {bc, bc, bc, bc};
            acc0 = __builtin_amdgcn_mfma_f32_16x16x32_bf16(a00, b0, acc0, 0, 0, 0);
            acc0 = __builtin_amdgcn_mfma_f32_16x16x32_bf16(a01, b1, acc0, 0, 0, 0);
            acc1 = __builtin_amdgcn_mfma_f32_16x16x32_bf16(a10, b0, acc1, 0, 0, 0);
            acc1 = __builtin_amdgcn_mfma_f32_16x16x32_bf16(a11, b1, acc1, 0, 0, 0);
            #pragma unroll
            for (int g = 0; g < 4; ++g) {            // C/D: row=q*4+g, col=lane&15
                myh1[(q * 4 + g) * LSTR + col]      = bf16r(fmaxf(acc0[g], 0.0f));
                myh1[(16 + q * 4 + g) * LSTR + col] = bf16r(fmaxf(acc1[g], 0.0f));
            }
        }

        const frag8 c00 = *(const frag8*)&myh1[lq * LSTR + q * 8];
        const frag8 c01 = *(const frag8*)&myh1[lq * LSTR + 32 + q * 8];
        const frag8 c10 = *(const frag8*)&myh1[(16 + lq) * LSTR + q * 8];
        const frag8 c11 = *(const frag8*)&myh1[(16 + lq) * LSTR + 32 + q * 8];

        #pragma unroll
        for (int t = 0; t < 3; ++t) {                // stage 2 -> image in slab
            int col = t * 16 + lq;                   // (same LSTR stride: pads live)
            frag8 b0 = *(const frag8*)&w2r[(col << 6) + q * 8];
            frag8 b1 = *(const frag8*)&w2r[(col << 6) + 32 + q * 8];
            frag4f acc0 = {0.f, 0.f, 0.f, 0.f};
            frag4f acc1 = {0.f, 0.f, 0.f, 0.f};
            acc0 = __builtin_amdgcn_mfma_f32_16x16x32_bf16(c00, b0, acc0, 0, 0, 0);
            acc0 = __builtin_amdgcn_mfma_f32_16x16x32_bf16(c01, b1, acc0, 0, 0, 0);
            acc1 = __builtin_amdgcn_mfma_f32_16x16x32_bf16(c10, b0, acc1, 0, 0, 0);
            acc1 = __builtin_amdgcn_mfma_f32_16x16x32_bf16(c11, b1, acc1, 0, 0, 0);
            #pragma unroll
            for (int g = 0; g < 4; ++g) {
                myh1[(q * 4 + g) * LSTR + col]      = bf16r(acc0[g]);
                myh1[(16 + q * 4 + g) * LSTR + col] = bf16r(acc1[g]);
            }
        }

        // copy-out: 32 rows x 96 B = 3072 contiguous bytes in rel-major H2
        unsigned short* dst = H2 + ((size_t)r * NN + nb) * H2R;
        #pragma unroll
        for (int i3 = 0; i3 < 3; ++i3) {
            int fl    = i3 * 64 + ln;                // 0..191 uint4v pieces
            int row   = fl / 6, piece = fl - row * 6;
            int n     = nb + row;
            if (n < NN)
                *(uint4v*)(dst + fl * 8) =
                    *(const uint4v*)&myh1[row * LSTR + piece * 8];
        }
    }
}

// ---- k4: gather fused with FIFO un-binning ---------------------------------
// One block per 16-node bucket (192 thr = 16 nodes x 12 lanes). Phase 1:
// cooperatively read the bucket's 8 FIFO segments (sequential), bin into
// per-node LDS lists. Phase 2: each node's 12 lanes accumulate its list with
// batched random H2 row reads (same inner loop as before).
__global__ __launch_bounds__(192) void gather_kernel(
    const unsigned short* __restrict__ H2, const uint2* __restrict__ fifo,
    const int* __restrict__ cur, const int* __restrict__ ovf_cnt,
    const uint2* __restrict__ ovf, const float* __restrict__ B2,
    float* __restrict__ out)
{
    __shared__ int lcnt[16];
    __shared__ unsigned lslot[16][LCAP];             // 4.5 KB
    int b   = blockIdx.x;
    int tid = threadIdx.x;
    if (tid < 16) lcnt[tid] = 0;
    __syncthreads();

    for (int s = 0; s < NSEG; ++s) {
        int cs = min(cur[s * NB + b], FCAP);
        const uint2* f = fifo + (size_t)(s * NB + b) * FCAP;
        for (int i = tid; i < cs; i += 192) {
            uint2 e = f[i];
            int j = (int)e.y;
            int pos = atomicAdd(&lcnt[j], 1);
            if (pos < LCAP) lslot[j][pos] = e.x;     // LCAP 72 >= max degree ~58
        }
    }
    __syncthreads();

    int j = tid / 12;
    int c = tid - j * 12;
    int n = b * 16 + j;
    int total = min(lcnt[j], LCAP);

    float a0 = 0.f, a1 = 0.f, a2 = 0.f, a3 = 0.f;
    int e = 0;
    for (; e + 8 <= total; e += 8) {
        unsigned p[8];
        #pragma unroll
        for (int k = 0; k < 8; ++k) p[k] = lslot[j][e + k];
        uint2 v[8];
        #pragma unroll
        for (int k = 0; k < 8; ++k)
            v[k] = ((const uint2*)(H2 + (size_t)(p[k] >> 13) * H2R))[c];
        #pragma unroll
        for (int k = 0; k < 8; ++k) {
            float nm = (float)(p[k] & 8191u) * (1.0f / 8192.0f);
            a0 = fmaf(__uint_as_float(v[k].x << 16),         nm, a0);
            a1 = fmaf(__uint_as_float(v[k].x & 0xFFFF0000u), nm, a1);
            a2 = fmaf(__uint_as_float(v[k].y << 16),         nm, a2);
            a3 = fmaf(__uint_as_float(v[k].y & 0xFFFF0000u), nm, a3);
        }
    }
    for (; e < total; ++e) {
        unsigned p = lslot[j][e];
        float nm = (float)(p & 8191u) * (1.0f / 8192.0f);
        uint2 v = ((const uint2*)(H2 + (size_t)(p >> 13) * H2R))[c];
        a0 = fmaf(__uint_as_float(v.x << 16),         nm, a0);
        a1 = fmaf(__uint_as_float(v.x & 0xFFFF0000u), nm, a1);
        a2 = fmaf(__uint_as_float(v.y << 16),         nm, a2);
        a3 = fmaf(__uint_as_float(v.y & 0xFFFF0000u), nm, a3);
    }
    // overflow list (typically empty): add entries targeting this node
    int ov = *ovf_cnt;
    if (ov > 0) {
        if (ov > OVF_CAP) ov = OVF_CAP;
        for (int i = 0; i < ov; ++i) {
            uint2 t = ovf[i];
            if ((int)t.x == n) {
                float nm = (float)(t.y & 8191u) * (1.0f / 8192.0f);
                uint2 v = ((const uint2*)(H2 + (size_t)(t.y >> 13) * H2R))[c];
                a0 = fmaf(__uint_as_float(v.x << 16),         nm, a0);
                a1 = fmaf(__uint_as_float(v.x & 0xFFFF0000u), nm, a1);
                a2 = fmaf(__uint_as_float(v.y << 16),         nm, a2);
                a3 = fmaf(__uint_as_float(v.y & 0xFFFF0000u), nm, a3);
            }
        }
    }
    float4 bbb = ((const float4*)B2)[c];
    ((float4*)out)[(size_t)n * 12u + c] = make_float4(
        fmaxf(a0 + bbb.x, 0.f), fmaxf(a1 + bbb.y, 0.f),
        fmaxf(a2 + bbb.z, 0.f), fmaxf(a3 + bbb.w, 0.f));
}

extern "C" void kernel_launch(void* const* d_in, const int* in_sizes, int n_in,
                              void* d_out, int out_size, void* d_ws, size_t ws_size,
                              hipStream_t stream) {
    const float* X   = (const float*)d_in[0];
    const float* nrm = (const float*)d_in[1];
    const float* W1  = (const float*)d_in[2];
    const float* W2  = (const float*)d_in[3];
    const float* B1  = (const float*)d_in[4];
    const float* B2  = (const float*)d_in[5];
    const int*   src = (const int*)d_in[6];
    const int*   dst = (const int*)d_in[7];
    const int*   rel = (const int*)d_in[8];
    float* out = (float*)d_out;

    // ws: H2 38.4MB | fifo 25.6MB | W1t/W2t 96KB | cur 100KB | ovf 512KB
    unsigned short* H2   = (unsigned short*)d_ws;
    uint2*          fifo = (uint2*)(H2 + (size_t)NN * RR * H2R);
    unsigned short* W1t  = (unsigned short*)(fifo + (size_t)NSEG * NB * FCAP);
    unsigned short* W2t  = W1t + RR * 48 * 64;
    int*            cur  = (int*)(W2t + RR * 48 * 64);
    int*            ovf_cnt = cur + NSEG * NB;       // zeroed with cur
    uint2*          ovf  = (uint2*)(ovf_cnt + 4);

    pre_kernel<<<K1GRID, 256, 0, stream>>>(W1, W2, W1t, W2t, cur);

    place_kernel<<<PB, 256, 0, stream>>>(
        src, dst, rel, nrm, cur, ovf_cnt, ovf, fifo);

    h2_kernel<<<H2TILES, 256, 0, stream>>>(X, W1t, W2t, B1, H2);

    gather_kernel<<<NB, 192, 0, stream>>>(
        H2, fifo, cur, ovf_cnt, ovf, B2, out);
}